// Round 1
// baseline (622.558 us; speedup 1.0000x reference)
//
#include <hip/hip_runtime.h>
#include <hip/hip_bf16.h>
#include <stdint.h>

// ---------------------------------------------------------------------------
// Bahdanau additive attention, B=32, T=2048, D=U=1024. fp32 in/out.
// Outputs (fp32, flat): ctx [32*1024] then weights [32*2048].
// Round 7: one-time values fp32->bf16 convert pass (fused into k_prep grid),
// GEMM A-staging switched to global_load_lds DMA (mirrors B path exactly).
// Falls back to in-loop fp32 staging if workspace is too small for bf16 copy.
// ---------------------------------------------------------------------------

typedef unsigned short ushort_t;
typedef short bf16x8 __attribute__((ext_vector_type(8)));
typedef float f32x4 __attribute__((ext_vector_type(4)));

#define GLOBAL_AS __attribute__((address_space(1)))
#define LDS_AS    __attribute__((address_space(3)))

__device__ __forceinline__ ushort_t f2bf(float f) {
    union { float f; unsigned int u; } v;
    v.f = f;
    unsigned int u = v.u;
    unsigned int r = u + 0x7FFFu + ((u >> 16) & 1u);  // RNE
    return (ushort_t)(r >> 16);
}
__device__ __forceinline__ unsigned int pk2(float a, float b) {
    union { __hip_bfloat162 h; unsigned int u; } c;
    c.h = __float22bfloat162_rn(make_float2(a, b));  // v_cvt_pk_bf16_f32
    return c.u;
}
__device__ __forceinline__ float fast_tanh(float x) {
    float ax = __builtin_fabsf(x);
    float e = __expf(-2.0f * ax);
    float t = (1.0f - e) * __builtin_amdgcn_rcpf(1.0f + e);
    return __builtin_copysignf(t, x);
}

static constexpr int B_ = 32, T_ = 2048, D_ = 1024, U_ = 1024;
static constexpr int M_ = B_ * T_;  // 65536
static constexpr int TRANS_B = 1024;
static constexpr int QPROJ_B = 512;
static constexpr int CONV_B  = 4096;  // (M_*D_/8 chunks) / (256 thr * 8 chunks)

// ---------------- kernel 1: fused prep (transpose | qproj | convert) -------
__global__ __launch_bounds__(256) void k_prep(const float* __restrict__ W2,
                                              const float* __restrict__ query,
                                              const float* __restrict__ W1,
                                              const float* __restrict__ b1,
                                              const float* __restrict__ b2,
                                              const float* __restrict__ values,
                                              ushort_t* __restrict__ W2T,
                                              float* __restrict__ qpb,
                                              ushort_t* __restrict__ vb) {
    __shared__ float smem[1280];
    int bid = blockIdx.x;
    const int tid = threadIdx.x;

    if (bid < TRANS_B) {  // W2 [D][U] -> W2T [U][D] bf16
        float(*tile)[33] = (float(*)[33])smem;
        int u0 = (bid & 31) * 32, d0 = (bid >> 5) * 32;
        int tx = tid & 31, ty = tid >> 5;
#pragma unroll
        for (int r = 0; r < 4; ++r)
            tile[ty + r * 8][tx] = W2[(size_t)(d0 + ty + r * 8) * U_ + (u0 + tx)];
        __syncthreads();
#pragma unroll
        for (int r = 0; r < 4; ++r)
            W2T[(size_t)(u0 + ty + r * 8) * D_ + (d0 + tx)] = f2bf(tile[tx][ty + r * 8]);
        return;
    }
    bid -= TRANS_B;

    if (bid >= QPROJ_B) {  // values fp32 -> bf16 (only launched in bf16 mode)
        const int cb = bid - QPROJ_B;  // 0..CONV_B-1
        const size_t base = (size_t)cb * 2048 + tid;
#pragma unroll
        for (int k = 0; k < 8; ++k) {
            const size_t chunk = base + (size_t)k * 256;  // 8 floats per chunk
            const float* s = values + chunk * 8;
            f32x4 v0 = *(const f32x4*)s;
            f32x4 v1 = *(const f32x4*)(s + 4);
            uint4 p;
            p.x = pk2(v0[0], v0[1]);
            p.y = pk2(v0[2], v0[3]);
            p.z = pk2(v1[0], v1[1]);
            p.w = pk2(v1[2], v1[3]);
            *(uint4*)(vb + chunk * 8) = p;
        }
        return;
    }

    // qproj: qpb[b][u] = query[b]@W1[:,u] + b1[u] + b2[u]
    const int b = bid >> 4, uc = bid & 15;
    float* qs = smem;          // [1024]
    float* red = smem + 1024;  // [256]
    for (int i = tid; i < D_; i += 256) qs[i] = query[b * D_ + i];
    __syncthreads();
    const int ul = tid & 63, ds = tid >> 6;
    const int u = uc * 64 + ul;
    float acc = 0.f;
#pragma unroll 8
    for (int d = ds * 256; d < ds * 256 + 256; ++d)
        acc += qs[d] * W1[(size_t)d * U_ + u];
    red[tid] = acc;
    __syncthreads();
    if (tid < 64) {
        int uu = uc * 64 + tid;
        qpb[b * U_ + uu] = red[tid] + red[tid + 64] + red[tid + 128] + red[tid + 192] +
                           b1[uu] + b2[uu];
    }
}

// ---------------- kernel 2: fused GEMM + tanh + Wv-dot ---------------------
// ABF16=1: both tiles staged via global_load_lds DMA from bf16 sources
// (source-side swizzle: LDS position p of row r holds source chunk p^(r&7)).
// ABF16=0: legacy path, A converted fp32->bf16 through VGPRs in-loop.
#define BM 128
#define BN 128
#define BK 64

template <bool ABF16>
__global__ __launch_bounds__(256) void k_score_gemm(const float* __restrict__ values,
                                                    const ushort_t* __restrict__ vb,
                                                    const ushort_t* __restrict__ W2T,
                                                    const float* __restrict__ qpb,
                                                    const float* __restrict__ Wv,
                                                    float* __restrict__ scores_partial) {
    __shared__ ushort_t As[BM * BK];  // 16 KB
    __shared__ ushort_t Bs[BN * BK];  // 16 KB
    __shared__ float sScore[BM];

    const int tid = threadIdx.x;
    const int lane = tid & 63;
    const int w = tid >> 6;
    const int wm = w >> 1, wn = w & 1;

    // XCD-grouped order: the 8 n-blocks of an m-tile get adjacent block ids
    const int g = blockIdx.x;
    const int mt = ((g >> 6) << 3) | (g & 7);
    const int nt = (g >> 3) & 7;
    const int m0 = mt * BM, n0 = nt * BN;

    if (tid < BM) sScore[tid] = 0.f;

    f32x4 acc[4][4];
#pragma unroll
    for (int i = 0; i < 4; ++i)
#pragma unroll
        for (int j = 0; j < 4; ++j) acc[i][j] = (f32x4){0.f, 0.f, 0.f, 0.f};

    // ---- DMA staging map (shared by A-bf16 and B): wave w, rows w*8+lr+i*32
    const int lr = lane >> 3;
    const int cB = (lane & 7) ^ lr;
    const ushort_t* bBase = W2T + (size_t)(n0 + w * 8 + lr) * D_ + cB * 8;
    const ushort_t* aBaseB = vb + (size_t)(m0 + w * 8 + lr) * D_ + cB * 8;

    // ---- legacy fp32 A staging map ----
    const int rA = tid >> 3;       // 0..31
    const int cA = tid & 7;        // source chunk (8 fp32)
    const int pA = cA ^ (rA & 7);  // swizzled LDS position
    const float* aSrc = values + (size_t)(m0 + rA) * D_ + cA * 8;
    ushort_t* aDst = As + rA * BK + pA * 8;

    const int quad = lane >> 4;
    const int l15 = lane & 15;
    const int l7 = l15 & 7;

    for (int k0 = 0; k0 < D_; k0 += BK) {
#pragma unroll
        for (int i = 0; i < 4; ++i) {
            __builtin_amdgcn_global_load_lds(
                (const GLOBAL_AS void*)(bBase + k0 + (size_t)i * 32 * D_),
                (LDS_AS void*)(Bs + i * 2048 + w * 512), 16, 0, 0);
        }
        if constexpr (ABF16) {
#pragma unroll
            for (int i = 0; i < 4; ++i) {
                __builtin_amdgcn_global_load_lds(
                    (const GLOBAL_AS void*)(aBaseB + k0 + (size_t)i * 32 * D_),
                    (LDS_AS void*)(As + i * 2048 + w * 512), 16, 0, 0);
            }
        } else {
#pragma unroll
            for (int i = 0; i < 4; ++i) {
                f32x4 v0 = *(const f32x4*)(aSrc + k0 + (size_t)i * 32 * D_);
                f32x4 v1 = *(const f32x4*)(aSrc + k0 + (size_t)i * 32 * D_ + 4);
                uint4 p;
                p.x = pk2(v0[0], v0[1]);
                p.y = pk2(v0[2], v0[3]);
                p.z = pk2(v1[0], v1[1]);
                p.w = pk2(v1[2], v1[3]);
                *(uint4*)(aDst + i * 32 * BK) = p;
            }
        }
        __syncthreads();
#pragma unroll
        for (int kk = 0; kk < BK; kk += 32) {
            bf16x8 af[4], bfr[4];
            const int cb = kk >> 3;  // 0 or 4
#pragma unroll
            for (int i = 0; i < 4; ++i) {
                int r = wm * 64 + i * 16 + l15;
                af[i] = *(const bf16x8*)(As + (r << 6) + (((quad + cb) ^ l7) << 3));
            }
#pragma unroll
            for (int j = 0; j < 4; ++j) {
                int r = wn * 64 + j * 16 + l15;
                bfr[j] = *(const bf16x8*)(Bs + (r << 6) + (((quad + cb) ^ l7) << 3));
            }
#pragma unroll
            for (int i = 0; i < 4; ++i)
#pragma unroll
                for (int j = 0; j < 4; ++j)
                    acc[i][j] = __builtin_amdgcn_mfma_f32_16x16x32_bf16(
                        af[i], bfr[j], acc[i][j], 0, 0, 0);
        }
        __syncthreads();
    }

    // epilogue: C row = wm*64+i*16+quad*4+r, col(u) = n0+wn*64+j*16+l15
    const int b = m0 >> 11;
    const float* qp = qpb + b * U_;
    float qv[4], wv[4];
#pragma unroll
    for (int j = 0; j < 4; ++j) {
        int u = n0 + wn * 64 + j * 16 + l15;
        qv[j] = qp[u];
        wv[j] = Wv[u];
    }
#pragma unroll
    for (int i = 0; i < 4; ++i) {
#pragma unroll
        for (int r = 0; r < 4; ++r) {
            float s = 0.f;
#pragma unroll
            for (int j = 0; j < 4; ++j) s += fast_tanh(acc[i][j][r] + qv[j]) * wv[j];
            s += __shfl_xor(s, 1);
            s += __shfl_xor(s, 2);
            s += __shfl_xor(s, 4);
            s += __shfl_xor(s, 8);
            if (l15 == 0) atomicAdd(&sScore[wm * 64 + i * 16 + quad * 4 + r], s);
        }
    }
    __syncthreads();
    if (tid < BM) scores_partial[(size_t)(m0 + tid) * 8 + nt] = sScore[tid];
}

// ---------------- kernel 3: softmax over T per batch -----------------------
__global__ __launch_bounds__(256) void k_softmax(const float* __restrict__ scores_partial,
                                                 const float* __restrict__ bv,
                                                 float* __restrict__ w_f,
                                                 float* __restrict__ out_w) {
    const int b = blockIdx.x;
    __shared__ float s[T_];
    __shared__ float red[4];
    const int tid = threadIdx.x;
    const float bvf = bv[0];

    float lmax = -1e30f;
    for (int t = tid; t < T_; t += 256) {
        const float* p = scores_partial + (size_t)(b * T_ + t) * 8;
        float sc = ((p[0] + p[1]) + (p[2] + p[3])) + ((p[4] + p[5]) + (p[6] + p[7])) + bvf;
        s[t] = sc;
        lmax = fmaxf(lmax, sc);
    }
    for (int off = 32; off; off >>= 1) lmax = fmaxf(lmax, __shfl_xor(lmax, off));
    if ((tid & 63) == 0) red[tid >> 6] = lmax;
    __syncthreads();
    const float gmax = fmaxf(fmaxf(red[0], red[1]), fmaxf(red[2], red[3]));

    float lsum = 0.f;
    for (int t = tid; t < T_; t += 256) {
        float e = __expf(s[t] - gmax);
        s[t] = e;
        lsum += e;
    }
    for (int off = 32; off; off >>= 1) lsum += __shfl_xor(lsum, off);
    __syncthreads();
    if ((tid & 63) == 0) red[tid >> 6] = lsum;
    __syncthreads();
    const float ginv = 1.f / ((red[0] + red[1]) + (red[2] + red[3]));

    for (int t = tid; t < T_; t += 256) {
        float wgt = s[t] * ginv;
        w_f[b * T_ + t] = wgt;
        out_w[b * T_ + t] = wgt;
    }
}

// -------- kernel 4: ctx partials (fp32), atomic finish into out_ctx --------
__global__ __launch_bounds__(256) void k_ctx(const float* __restrict__ values,
                                             const float* __restrict__ w_f,
                                             float* __restrict__ out_ctx) {
    const int tc = blockIdx.x;  // 0..15
    const int b = blockIdx.y;   // 0..31
    const int tid = threadIdx.x;
    __shared__ float wls[128];
    if (tid < 128) wls[tid] = w_f[b * T_ + tc * 128 + tid];
    __syncthreads();

    f32x4 acc = (f32x4){0.f, 0.f, 0.f, 0.f};
    const float* base = values + (size_t)(b * T_ + tc * 128) * D_ + tid * 4;
#pragma unroll 4
    for (int tt = 0; tt < 128; ++tt)
        acc += wls[tt] * *(const f32x4*)(base + (size_t)tt * D_);
    float* out = out_ctx + b * D_ + tid * 4;
    atomicAdd(&out[0], acc[0]);
    atomicAdd(&out[1], acc[1]);
    atomicAdd(&out[2], acc[2]);
    atomicAdd(&out[3], acc[3]);
}

// ---------------------------------------------------------------------------
extern "C" void kernel_launch(void* const* d_in, const int* in_sizes, int n_in,
                              void* d_out, int out_size, void* d_ws, size_t ws_size,
                              hipStream_t stream) {
    const float* query  = (const float*)d_in[0];
    const float* values = (const float*)d_in[1];
    const float* W1     = (const float*)d_in[2];
    const float* b1     = (const float*)d_in[3];
    const float* W2     = (const float*)d_in[4];
    const float* b2     = (const float*)d_in[5];
    const float* Wv     = (const float*)d_in[6];
    const float* bv     = (const float*)d_in[7];

    float* out_ctx = (float*)d_out;          // [32*1024]
    float* out_w   = out_ctx + B_ * D_;      // [32*2048]

    char* ws = (char*)d_ws;
    const size_t OFF_W2T = 0;                 // 2 MB bf16
    const size_t OFF_QPB = 0x200000;          // 128 KB
    const size_t OFF_SP  = 0x220000;          // 2 MB
    const size_t OFF_WF  = 0x420000;          // 256 KB
    const size_t OFF_VB  = 0x500000;          // 128 MB bf16 values (optional)
    const size_t VB_BYTES = (size_t)M_ * D_ * sizeof(ushort_t);

    ushort_t* W2T            = (ushort_t*)(ws + OFF_W2T);
    float*    qpb            = (float*)(ws + OFF_QPB);
    float*    scores_partial = (float*)(ws + OFF_SP);
    float*    w_f            = (float*)(ws + OFF_WF);
    ushort_t* vb             = (ushort_t*)(ws + OFF_VB);

    const bool use_bf16 = (ws_size >= OFF_VB + VB_BYTES);

    // out_ctx accumulated via atomics; zero it first (graph-capture legal)
    hipMemsetAsync(out_ctx, 0, (size_t)B_ * D_ * sizeof(float), stream);

    k_prep<<<dim3(TRANS_B + QPROJ_B + (use_bf16 ? CONV_B : 0)), 256, 0, stream>>>(
        W2, query, W1, b1, b2, values, W2T, qpb, vb);
    if (use_bf16) {
        k_score_gemm<true><<<dim3((M_ / BM) * (U_ / BN)), 256, 0, stream>>>(
            values, vb, W2T, qpb, Wv, scores_partial);
    } else {
        k_score_gemm<false><<<dim3((M_ / BM) * (U_ / BN)), 256, 0, stream>>>(
            values, vb, W2T, qpb, Wv, scores_partial);
    }
    k_softmax<<<dim3(B_), 256, 0, stream>>>(scores_partial, bv, w_f, out_w);
    k_ctx<<<dim3(16, B_), 256, 0, stream>>>(values, w_f, out_ctx);

    (void)in_sizes; (void)n_in; (void)out_size; (void)ws_size;
}

// Round 2
// 607.237 us; speedup vs baseline: 1.0252x; 1.0252x over previous
//
#include <hip/hip_runtime.h>
#include <hip/hip_bf16.h>
#include <stdint.h>

// ---------------------------------------------------------------------------
// Bahdanau additive attention, B=32, T=2048, D=U=1024. fp32 in/out.
// Outputs (fp32, flat): ctx [32*1024] then weights [32*2048].
// Round 8: no standalone convert pass (net-negative last round). A staged
// in-GEMM fp32->bf16 with T14 async-split (prefetch next K-tile regs after
// barrier so HBM latency hides under MFMA). B via global_load_lds (proven,
// 0 bank conflicts). k_ctx: non-atomic partials + reduce (no memset, no
// 524K cross-XCD atomics). qproj v2: W1 read once per 8 batches (8x less).
// ---------------------------------------------------------------------------

typedef unsigned short ushort_t;
typedef short bf16x8 __attribute__((ext_vector_type(8)));
typedef float f32x4 __attribute__((ext_vector_type(4)));

#define GLOBAL_AS __attribute__((address_space(1)))
#define LDS_AS    __attribute__((address_space(3)))

__device__ __forceinline__ ushort_t f2bf(float f) {
    union { float f; unsigned int u; } v;
    v.f = f;
    unsigned int u = v.u;
    unsigned int r = u + 0x7FFFu + ((u >> 16) & 1u);  // RNE
    return (ushort_t)(r >> 16);
}
__device__ __forceinline__ unsigned int pk2(float a, float b) {
    union { __hip_bfloat162 h; unsigned int u; } c;
    c.h = __float22bfloat162_rn(make_float2(a, b));  // v_cvt_pk_bf16_f32
    return c.u;
}
__device__ __forceinline__ float fast_tanh(float x) {
    float ax = __builtin_fabsf(x);
    float e = __expf(-2.0f * ax);
    float t = (1.0f - e) * __builtin_amdgcn_rcpf(1.0f + e);
    return __builtin_copysignf(t, x);
}

static constexpr int B_ = 32, T_ = 2048, D_ = 1024, U_ = 1024;
static constexpr int M_ = B_ * T_;  // 65536
static constexpr int TRANS_B = 1024;
static constexpr int QPROJ_B = 64;  // v2: (4 batch-groups of 8) x (16 u-chunks of 64)

// ---------------- kernel 1: fused prep (transpose | qproj v2) --------------
__global__ __launch_bounds__(256) void k_prep(const float* __restrict__ W2,
                                              const float* __restrict__ query,
                                              const float* __restrict__ W1,
                                              const float* __restrict__ b1,
                                              const float* __restrict__ b2,
                                              ushort_t* __restrict__ W2T,
                                              float* __restrict__ qpb) {
    __shared__ float smem[8192 + 4 * 64 * 9];  // qs[8][1024] | red[4][64][9(pad)]
    int bid = blockIdx.x;
    const int tid = threadIdx.x;

    if (bid < TRANS_B) {  // W2 [D][U] -> W2T [U][D] bf16
        float(*tile)[33] = (float(*)[33])smem;
        int u0 = (bid & 31) * 32, d0 = (bid >> 5) * 32;
        int tx = tid & 31, ty = tid >> 5;
#pragma unroll
        for (int r = 0; r < 4; ++r)
            tile[ty + r * 8][tx] = W2[(size_t)(d0 + ty + r * 8) * U_ + (u0 + tx)];
        __syncthreads();
#pragma unroll
        for (int r = 0; r < 4; ++r)
            W2T[(size_t)(u0 + ty + r * 8) * D_ + (d0 + tx)] = f2bf(tile[tx][ty + r * 8]);
        return;
    }
    const int qb = bid - TRANS_B;  // 0..63
    const int bg = qb >> 4;        // batch group of 8
    const int uc = qb & 15;        // 64-u chunk

    float* qs = smem;                 // [8][1024]
    float(*red)[64][9] = (float(*)[64][9])(smem + 8192);

    for (int i = tid; i < 8 * 1024; i += 256)
        qs[i] = query[(size_t)(bg * 8 + (i >> 10)) * D_ + (i & 1023)];
    __syncthreads();

    const int ul = tid & 63, ds = tid >> 6;
    const int u = uc * 64 + ul;
    float acc[8] = {0.f, 0.f, 0.f, 0.f, 0.f, 0.f, 0.f, 0.f};
#pragma unroll 8
    for (int d = ds * 256; d < ds * 256 + 256; ++d) {
        const float w = W1[(size_t)d * U_ + u];
#pragma unroll
        for (int b = 0; b < 8; ++b) acc[b] += qs[(b << 10) + d] * w;  // LDS broadcast
    }
#pragma unroll
    for (int b = 0; b < 8; ++b) red[ds][ul][b] = acc[b];
    __syncthreads();
    for (int i = tid; i < 512; i += 256) {
        const int b = i & 7, uu = i >> 3;
        const float s = (red[0][uu][b] + red[1][uu][b]) + (red[2][uu][b] + red[3][uu][b]);
        const int ug = uc * 64 + uu;
        qpb[(size_t)(bg * 8 + b) * U_ + ug] = s + b1[ug] + b2[ug];
    }
}

// ---------------- kernel 2: fused GEMM + tanh + Wv-dot ---------------------
// A: fp32 from values, converted in-flight (T14: regs loaded one K-tile
// ahead, issued right after the barrier so latency hides under MFMA).
// B: bf16 DMA via global_load_lds. Both tiles XOR-swizzled at 16B chunks:
// LDS position p of row r holds source chunk p ^ (r&7).
#define BM 128
#define BN 128
#define BK 64

__global__ __launch_bounds__(256) void k_score_gemm(const float* __restrict__ values,
                                                    const ushort_t* __restrict__ W2T,
                                                    const float* __restrict__ qpb,
                                                    const float* __restrict__ Wv,
                                                    float* __restrict__ scores_partial) {
    __shared__ ushort_t As[BM * BK];  // 16 KB
    __shared__ ushort_t Bs[BN * BK];  // 16 KB
    __shared__ float sScore[BM];

    const int tid = threadIdx.x;
    const int lane = tid & 63;
    const int w = tid >> 6;
    const int wm = w >> 1, wn = w & 1;

    // XCD-grouped order: the 8 n-blocks of an m-tile get adjacent block ids
    const int g = blockIdx.x;
    const int mt = ((g >> 6) << 3) | (g & 7);
    const int nt = (g >> 3) & 7;
    const int m0 = mt * BM, n0 = nt * BN;

    if (tid < BM) sScore[tid] = 0.f;

    f32x4 acc[4][4];
#pragma unroll
    for (int i = 0; i < 4; ++i)
#pragma unroll
        for (int j = 0; j < 4; ++j) acc[i][j] = (f32x4){0.f, 0.f, 0.f, 0.f};

    // ---- B DMA staging map: wave w, rows w*8+lr+i*32, source-side swizzle
    const int lr = lane >> 3;
    const int cB = (lane & 7) ^ lr;
    const ushort_t* bBase = W2T + (size_t)(n0 + w * 8 + lr) * D_ + cB * 8;

    // ---- A staging map: iteration i covers rows i*32 + (tid>>3) ----
    const int rA = tid >> 3;       // 0..31
    const int cA = tid & 7;        // source chunk (8 fp32)
    const int pA = cA ^ (rA & 7);  // swizzled LDS position
    const float* aSrc = values + (size_t)(m0 + rA) * D_ + cA * 8;
    ushort_t* aDst = As + rA * BK + pA * 8;

    const int quad = lane >> 4;
    const int l15 = lane & 15;
    const int l7 = l15 & 7;

    // T14 prologue: load K-tile 0 into registers
    f32x4 ra0[4], ra1[4];
#pragma unroll
    for (int i = 0; i < 4; ++i) {
        ra0[i] = *(const f32x4*)(aSrc + (size_t)i * 32 * D_);
        ra1[i] = *(const f32x4*)(aSrc + (size_t)i * 32 * D_ + 4);
    }

    for (int k0 = 0; k0 < D_; k0 += BK) {
        // B DMA first: runs while A converts through VALU
#pragma unroll
        for (int i = 0; i < 4; ++i) {
            __builtin_amdgcn_global_load_lds(
                (const GLOBAL_AS void*)(bBase + k0 + (size_t)i * 32 * D_),
                (LDS_AS void*)(Bs + i * 2048 + w * 512), 16, 0, 0);
        }
        // convert the pre-staged registers for THIS K-tile into LDS
#pragma unroll
        for (int i = 0; i < 4; ++i) {
            uint4 p;
            p.x = pk2(ra0[i][0], ra0[i][1]);
            p.y = pk2(ra0[i][2], ra0[i][3]);
            p.z = pk2(ra1[i][0], ra1[i][1]);
            p.w = pk2(ra1[i][2], ra1[i][3]);
            *(uint4*)(aDst + i * 32 * BK) = p;
        }
        __syncthreads();
        // T14: issue next K-tile's A loads now; latency hides under MFMA
        if (k0 + BK < D_) {
#pragma unroll
            for (int i = 0; i < 4; ++i) {
                ra0[i] = *(const f32x4*)(aSrc + k0 + BK + (size_t)i * 32 * D_);
                ra1[i] = *(const f32x4*)(aSrc + k0 + BK + (size_t)i * 32 * D_ + 4);
            }
        }
#pragma unroll
        for (int kk = 0; kk < BK; kk += 32) {
            bf16x8 af[4], bfr[4];
            const int cb = kk >> 3;  // 0 or 4
#pragma unroll
            for (int i = 0; i < 4; ++i) {
                int r = wm * 64 + i * 16 + l15;
                af[i] = *(const bf16x8*)(As + (r << 6) + (((quad + cb) ^ l7) << 3));
            }
#pragma unroll
            for (int j = 0; j < 4; ++j) {
                int r = wn * 64 + j * 16 + l15;
                bfr[j] = *(const bf16x8*)(Bs + (r << 6) + (((quad + cb) ^ l7) << 3));
            }
#pragma unroll
            for (int i = 0; i < 4; ++i)
#pragma unroll
                for (int j = 0; j < 4; ++j)
                    acc[i][j] = __builtin_amdgcn_mfma_f32_16x16x32_bf16(
                        af[i], bfr[j], acc[i][j], 0, 0, 0);
        }
        __syncthreads();
    }

    // epilogue: C row = wm*64+i*16+quad*4+r, col(u) = n0+wn*64+j*16+l15
    const int b = m0 >> 11;
    const float* qp = qpb + b * U_;
    float qv[4], wv[4];
#pragma unroll
    for (int j = 0; j < 4; ++j) {
        int u = n0 + wn * 64 + j * 16 + l15;
        qv[j] = qp[u];
        wv[j] = Wv[u];
    }
#pragma unroll
    for (int i = 0; i < 4; ++i) {
#pragma unroll
        for (int r = 0; r < 4; ++r) {
            float s = 0.f;
#pragma unroll
            for (int j = 0; j < 4; ++j) s += fast_tanh(acc[i][j][r] + qv[j]) * wv[j];
            s += __shfl_xor(s, 1);
            s += __shfl_xor(s, 2);
            s += __shfl_xor(s, 4);
            s += __shfl_xor(s, 8);
            if (l15 == 0) atomicAdd(&sScore[wm * 64 + i * 16 + quad * 4 + r], s);
        }
    }
    __syncthreads();
    if (tid < BM) scores_partial[(size_t)(m0 + tid) * 8 + nt] = sScore[tid];
}

// ---------------- kernel 3: softmax over T per batch -----------------------
__global__ __launch_bounds__(256) void k_softmax(const float* __restrict__ scores_partial,
                                                 const float* __restrict__ bv,
                                                 float* __restrict__ w_f,
                                                 float* __restrict__ out_w) {
    const int b = blockIdx.x;
    __shared__ float s[T_];
    __shared__ float red[4];
    const int tid = threadIdx.x;
    const float bvf = bv[0];

    float lmax = -1e30f;
    for (int t = tid; t < T_; t += 256) {
        const float* p = scores_partial + (size_t)(b * T_ + t) * 8;
        float sc = ((p[0] + p[1]) + (p[2] + p[3])) + ((p[4] + p[5]) + (p[6] + p[7])) + bvf;
        s[t] = sc;
        lmax = fmaxf(lmax, sc);
    }
    for (int off = 32; off; off >>= 1) lmax = fmaxf(lmax, __shfl_xor(lmax, off));
    if ((tid & 63) == 0) red[tid >> 6] = lmax;
    __syncthreads();
    const float gmax = fmaxf(fmaxf(red[0], red[1]), fmaxf(red[2], red[3]));

    float lsum = 0.f;
    for (int t = tid; t < T_; t += 256) {
        float e = __expf(s[t] - gmax);
        s[t] = e;
        lsum += e;
    }
    for (int off = 32; off; off >>= 1) lsum += __shfl_xor(lsum, off);
    __syncthreads();
    if ((tid & 63) == 0) red[tid >> 6] = lsum;
    __syncthreads();
    const float ginv = 1.f / ((red[0] + red[1]) + (red[2] + red[3]));

    for (int t = tid; t < T_; t += 256) {
        float wgt = s[t] * ginv;
        w_f[b * T_ + t] = wgt;
        out_w[b * T_ + t] = wgt;
    }
}

// -------- kernel 4: ctx partials (fp32, NON-atomic) ------------------------
__global__ __launch_bounds__(256) void k_ctx(const float* __restrict__ values,
                                             const float* __restrict__ w_f,
                                             float* __restrict__ ctx_part) {
    const int tc = blockIdx.x;  // 0..15
    const int b = blockIdx.y;   // 0..31
    const int tid = threadIdx.x;
    __shared__ float wls[128];
    if (tid < 128) wls[tid] = w_f[b * T_ + tc * 128 + tid];
    __syncthreads();

    f32x4 acc = (f32x4){0.f, 0.f, 0.f, 0.f};
    const float* base = values + (size_t)(b * T_ + tc * 128) * D_ + tid * 4;
#pragma unroll 4
    for (int tt = 0; tt < 128; ++tt)
        acc += wls[tt] * *(const f32x4*)(base + (size_t)tt * D_);
    *(f32x4*)(ctx_part + ((size_t)(tc * 32 + b) << 10) + tid * 4) = acc;
}

// -------- kernel 5: reduce 16 partials -> out_ctx --------------------------
__global__ __launch_bounds__(256) void k_ctx_fin(const float* __restrict__ ctx_part,
                                                 float* __restrict__ out_ctx) {
    const int b = blockIdx.x;  // 0..31
    const int tid = threadIdx.x;
    f32x4 s = (f32x4){0.f, 0.f, 0.f, 0.f};
#pragma unroll
    for (int tc = 0; tc < 16; ++tc)
        s += *(const f32x4*)(ctx_part + ((size_t)(tc * 32 + b) << 10) + tid * 4);
    *(f32x4*)(out_ctx + b * D_ + tid * 4) = s;
}

// ---------------------------------------------------------------------------
extern "C" void kernel_launch(void* const* d_in, const int* in_sizes, int n_in,
                              void* d_out, int out_size, void* d_ws, size_t ws_size,
                              hipStream_t stream) {
    const float* query  = (const float*)d_in[0];
    const float* values = (const float*)d_in[1];
    const float* W1     = (const float*)d_in[2];
    const float* b1     = (const float*)d_in[3];
    const float* W2     = (const float*)d_in[4];
    const float* b2     = (const float*)d_in[5];
    const float* Wv     = (const float*)d_in[6];
    const float* bv     = (const float*)d_in[7];

    float* out_ctx = (float*)d_out;          // [32*1024]
    float* out_w   = out_ctx + B_ * D_;      // [32*2048]

    char* ws = (char*)d_ws;
    const size_t OFF_W2T = 0;                 // 2 MB bf16
    const size_t OFF_QPB = 0x200000;          // 128 KB
    const size_t OFF_SP  = 0x220000;          // 2 MB
    const size_t OFF_WF  = 0x420000;          // 256 KB
    const size_t OFF_CP  = 0x460000;          // 2 MB ctx partials

    ushort_t* W2T            = (ushort_t*)(ws + OFF_W2T);
    float*    qpb            = (float*)(ws + OFF_QPB);
    float*    scores_partial = (float*)(ws + OFF_SP);
    float*    w_f            = (float*)(ws + OFF_WF);
    float*    ctx_part       = (float*)(ws + OFF_CP);

    k_prep<<<dim3(TRANS_B + QPROJ_B), 256, 0, stream>>>(W2, query, W1, b1, b2, W2T, qpb);
    k_score_gemm<<<dim3((M_ / BM) * (U_ / BN)), 256, 0, stream>>>(
        values, W2T, qpb, Wv, scores_partial);
    k_softmax<<<dim3(B_), 256, 0, stream>>>(scores_partial, bv, w_f, out_w);
    k_ctx<<<dim3(16, B_), 256, 0, stream>>>(values, w_f, ctx_part);
    k_ctx_fin<<<dim3(B_), 256, 0, stream>>>(ctx_part, out_ctx);

    (void)in_sizes; (void)n_in; (void)out_size; (void)ws_size;
}